// Round 2
// baseline (298.545 us; speedup 1.0000x reference)
//
#include <hip/hip_runtime.h>
#include <hip/hip_bf16.h>

// Problem constants
#define B_ 8
#define C_ 64
#define H_ 240
#define W_ 320
#define HW_ (H_ * W_)      // 76800
#define HW4_ (HW_ / 4)     // 19200
#define K_ 10
#define ALPHA_ 0.02f
#define DELTA_ 0.5f
#define MIN_WEIGHT_ 50.0f

#define K1_SPLIT 8         // pixel-splits in k1 -> 64*8*8 = 4096 blocks

// Workspace layout (floats):
//   [0, 5120)      sums[b*64+c][k]
//   [5120, 5200)   counts[b*10+k]
//   [5200, 10320)  means[b*64+c][k] (normalized)
//   [10320, 10400) S2[b*10+k]
//   [10400, 10480) Nk[b*10+k]
//   [10480]        indicator total
//   [10481]        inter_loss

// ---------------------------------------------------------------------------
// Kernel 1: masked channel sums + cluster counts.
// grid (64, 8, K1_SPLIT), block 256. Each block reduces one pixel-slice of
// one (b,c) plane. 4096 blocks -> 64 waves/CU (latency hidden).
// ---------------------------------------------------------------------------
__global__ __launch_bounds__(256) void k1_sums(
    const float* __restrict__ x, const int* __restrict__ cm,
    float* __restrict__ sums, float* __restrict__ counts) {
  const int c = blockIdx.x;
  const int b = blockIdx.y;
  const int z = blockIdx.z;
  const int tid = threadIdx.x;

  const int chunk = HW4_ / K1_SPLIT;  // 2400
  const int lo = z * chunk;
  const int hi = lo + chunk;

  const float4* __restrict__ xp =
      (const float4*)(x + (size_t)(b * C_ + c) * HW_);
  const int4* __restrict__ cp = (const int4*)(cm + (size_t)b * HW_);

  float acc[K_];
#pragma unroll
  for (int j = 0; j < K_; ++j) acc[j] = 0.f;
  float cnt[K_];
#pragma unroll
  for (int j = 0; j < K_; ++j) cnt[j] = 0.f;
  const bool do_cnt = (c == 0);

  for (int i = lo + tid; i < hi; i += 256) {
    float4 v = xp[i];
    int4 k4 = cp[i];
#pragma unroll
    for (int j = 0; j < K_; ++j) {
      acc[j] += (k4.x == j ? v.x : 0.f);
      acc[j] += (k4.y == j ? v.y : 0.f);
      acc[j] += (k4.z == j ? v.z : 0.f);
      acc[j] += (k4.w == j ? v.w : 0.f);
    }
    if (do_cnt) {
#pragma unroll
      for (int j = 0; j < K_; ++j) {
        cnt[j] += (float)((k4.x == j) + (k4.y == j) + (k4.z == j) + (k4.w == j));
      }
    }
  }

  // wave-level reduce (wave = 64 lanes), then one atomic per wave per bin
#pragma unroll
  for (int j = 0; j < K_; ++j) {
    float v = acc[j];
    for (int off = 32; off > 0; off >>= 1) v += __shfl_down(v, off, 64);
    if ((tid & 63) == 0) atomicAdd(&sums[(b * C_ + c) * K_ + j], v);
  }
  if (do_cnt) {
#pragma unroll
    for (int j = 0; j < K_; ++j) {
      float v = cnt[j];
      for (int off = 32; off > 0; off >>= 1) v += __shfl_down(v, off, 64);
      if ((tid & 63) == 0) atomicAdd(&counts[b * K_ + j], v);
    }
  }
}

// ---------------------------------------------------------------------------
// Kernel 2: normalize means + inter loss. One block of 256 threads.
// ---------------------------------------------------------------------------
__global__ __launch_bounds__(256) void k2_means(
    const float* __restrict__ sums, const float* __restrict__ counts,
    float* __restrict__ means, float* __restrict__ interloss) {
  const int tid = threadIdx.x;

  if (tid < B_ * K_) {
    const int b = tid / K_;
    const int k = tid % K_;
    const float inv = 1.f / (counts[tid] + 1e-10f);
    float m[C_];
    float nrm2 = 0.f;
#pragma unroll
    for (int c = 0; c < C_; ++c) {
      float mm = sums[(b * C_ + c) * K_ + k] * inv;
      m[c] = mm;
      nrm2 += mm * mm;
    }
    const float rn = 1.f / fmaxf(sqrtf(nrm2), 1e-12f);
#pragma unroll
    for (int c = 0; c < C_; ++c) means[(b * C_ + c) * K_ + k] = m[c] * rn;
  }
  __syncthreads();

  // inter loss: 8 batches x 45 unordered (k<l) pairs; each counted twice in ref
  float h2 = 0.f;
  for (int t = tid; t < B_ * 45; t += 256) {
    const int b = t / 45;
    int idx = t % 45;
    int k = 0, l = 0;
    for (k = 0; k < K_; ++k) {
      const int row = K_ - 1 - k;
      if (idx < row) { l = k + 1 + idx; break; }
      idx -= row;
    }
    float g = 0.f;
    for (int c = 0; c < C_; ++c)
      g += means[(b * C_ + c) * K_ + k] * means[(b * C_ + c) * K_ + l];
    const float inter_d = 0.5f * (1.f - g);
    const float h = fmaxf(DELTA_ - inter_d, 0.f);
    h2 += 2.f * h * h;  // (k,l) and (l,k)
  }

  __shared__ float red[256];
  red[tid] = h2;
  __syncthreads();
  for (int s = 128; s > 0; s >>= 1) {
    if (tid < s) red[tid] += red[tid + s];
    __syncthreads();
  }
  if (tid == 0) interloss[0] = red[0] / (float)((K_ * (K_ - 1) / 2) * B_);
}

// ---------------------------------------------------------------------------
// Kernel 3: per-pixel intra distance, accumulate S2 / Nk per cluster.
// Block = 64 pixel-lanes x 4 channel-groups (16 channels each), partial dots
// reduced through LDS. grid (300, 8) -> 9600 waves -> full occupancy, while
// keeping float4 (16 B/lane) global loads.
// ---------------------------------------------------------------------------
__global__ __launch_bounds__(256) void k3_intra(
    const float* __restrict__ x, const int* __restrict__ cm,
    const float* __restrict__ means, float* __restrict__ S2,
    float* __restrict__ Nk, float* __restrict__ indtot) {
  const int b = blockIdx.y;
  const int tid = threadIdx.x;
  const int lane_p = tid & 63;   // pixel-unit lane (one float4 = 4 pixels)
  const int grp = tid >> 6;      // channel group 0..3

  __shared__ float mlds[C_ * K_];   // 640 floats, layout [c*10+k]
  __shared__ float4 pd[256];        // partial dots per thread
  __shared__ float s2b[K_];
  __shared__ float nkb[K_];

  for (int i = tid; i < C_ * K_; i += 256) mlds[i] = means[b * C_ * K_ + i];
  if (tid < K_) { s2b[tid] = 0.f; nkb[tid] = 0.f; }
  __syncthreads();

  const int p4 = blockIdx.x * 64 + lane_p;  // 0..19199
  const int4 k4 = ((const int4*)(cm + (size_t)b * HW_))[p4];
  const float4* __restrict__ xb = (const float4*)(x + (size_t)b * C_ * HW_);

  float d0 = 0.f, d1 = 0.f, d2 = 0.f, d3 = 0.f;
  const int c0 = grp * (C_ / 4);
#pragma unroll
  for (int cc = 0; cc < C_ / 4; ++cc) {
    const int c = c0 + cc;
    float4 v = xb[c * HW4_ + p4];
    const float* mr = &mlds[c * K_];
    d0 += v.x * mr[k4.x];
    d1 += v.y * mr[k4.y];
    d2 += v.z * mr[k4.z];
    d3 += v.w * mr[k4.w];
  }
  pd[tid] = make_float4(d0, d1, d2, d3);
  __syncthreads();

  if (grp == 0) {
    float4 a = pd[lane_p];
    float4 bb = pd[lane_p + 64];
    float4 cc = pd[lane_p + 128];
    float4 dd = pd[lane_p + 192];
    const float i0 = 0.5f * (1.f - (a.x + bb.x + cc.x + dd.x));
    const float i1 = 0.5f * (1.f - (a.y + bb.y + cc.y + dd.y));
    const float i2 = 0.5f * (1.f - (a.z + bb.z + cc.z + dd.z));
    const float i3 = 0.5f * (1.f - (a.w + bb.w + cc.w + dd.w));

    atomicAdd(&s2b[k4.x], i0 * i0);
    atomicAdd(&s2b[k4.y], i1 * i1);
    atomicAdd(&s2b[k4.z], i2 * i2);
    atomicAdd(&s2b[k4.w], i3 * i3);
    atomicAdd(&nkb[k4.x], i0 > ALPHA_ ? 1.f : 0.f);
    atomicAdd(&nkb[k4.y], i1 > ALPHA_ ? 1.f : 0.f);
    atomicAdd(&nkb[k4.z], i2 > ALPHA_ ? 1.f : 0.f);
    atomicAdd(&nkb[k4.w], i3 > ALPHA_ ? 1.f : 0.f);
  }
  __syncthreads();

  if (tid < K_) {
    atomicAdd(&S2[b * K_ + tid], s2b[tid]);
    atomicAdd(&Nk[b * K_ + tid], nkb[tid]);
    atomicAdd(indtot, nkb[tid]);
  }
}

// ---------------------------------------------------------------------------
// Kernel 4: finalize — combine intra + inter, write 3 scalars.
// ---------------------------------------------------------------------------
__global__ void k4_final(const float* __restrict__ S2, const float* __restrict__ Nk,
                         const float* __restrict__ indtot,
                         const float* __restrict__ interloss,
                         float* __restrict__ out) {
  if (threadIdx.x == 0) {
    float intra = 0.f;
    for (int i = 0; i < B_ * K_; ++i) {
      const float w = fmaxf(Nk[i], MIN_WEIGHT_) * (float)K_;
      intra += S2[i] / w;
    }
    intra /= (float)B_;
    if (!(indtot[0] > 0.f)) intra = 0.f;
    const float inter = interloss[0];
    out[0] = intra + inter;
    out[1] = intra;
    out[2] = inter;
  }
}

extern "C" void kernel_launch(void* const* d_in, const int* in_sizes, int n_in,
                              void* d_out, int out_size, void* d_ws, size_t ws_size,
                              hipStream_t stream) {
  const float* x = (const float*)d_in[0];
  const int* cm = (const int*)d_in[1];

  float* ws = (float*)d_ws;
  float* sums = ws;             // 5120
  float* counts = ws + 5120;    // 80
  float* means = ws + 5200;     // 5120
  float* S2 = ws + 10320;       // 80
  float* Nk = ws + 10400;       // 80
  float* indtot = ws + 10480;   // 1
  float* interL = ws + 10481;   // 1

  // ws is re-poisoned to 0xAA before every call — zero the accumulators.
  hipMemsetAsync(d_ws, 0, 10482 * sizeof(float), stream);

  k1_sums<<<dim3(C_, B_, K1_SPLIT), 256, 0, stream>>>(x, cm, sums, counts);
  k2_means<<<1, 256, 0, stream>>>(sums, counts, means, interL);
  k3_intra<<<dim3(HW4_ / 64, B_), 256, 0, stream>>>(x, cm, means, S2, Nk, indtot);
  k4_final<<<1, 64, 0, stream>>>(S2, Nk, indtot, interL, (float*)d_out);
}

// Round 4
// 295.581 us; speedup vs baseline: 1.0100x; 1.0100x over previous
//
#include <hip/hip_runtime.h>
#include <hip/hip_bf16.h>

// Problem constants
#define B_ 8
#define C_ 64
#define H_ 240
#define W_ 320
#define HW_ (H_ * W_)      // 76800
#define HW4_ (HW_ / 4)     // 19200
#define K_ 10
#define ALPHA_ 0.02f
#define DELTA_ 0.5f
#define MIN_WEIGHT_ 50.0f

#define K1_SPLIT 8         // pixel-splits in k1 -> 64*8*8 = 4096 blocks

// Workspace layout (floats):
//   [0, 5120)      sums[b*64+c][k]
//   [5120, 5200)   counts[b*10+k]
//   [5200, 10320)  means[b*64+c][k] (normalized, written by k3 chunk-0 blocks)
//   [10320, 10400) S2[b*10+k]
//   [10400, 10480) Nk[b*10+k]
//   [10480]        indicator total

// ---------------------------------------------------------------------------
// Kernel 1: masked channel sums + cluster counts.
// grid (64, 8, K1_SPLIT), block 256.
// ---------------------------------------------------------------------------
__global__ __launch_bounds__(256) void k1_sums(
    const float* __restrict__ x, const int* __restrict__ cm,
    float* __restrict__ sums, float* __restrict__ counts) {
  const int c = blockIdx.x;
  const int b = blockIdx.y;
  const int z = blockIdx.z;
  const int tid = threadIdx.x;

  const int chunk = HW4_ / K1_SPLIT;  // 2400
  const int lo = z * chunk;
  const int hi = lo + chunk;

  const float4* __restrict__ xp =
      (const float4*)(x + (size_t)(b * C_ + c) * HW_);
  const int4* __restrict__ cp = (const int4*)(cm + (size_t)b * HW_);

  float acc[K_];
#pragma unroll
  for (int j = 0; j < K_; ++j) acc[j] = 0.f;
  float cnt[K_];
#pragma unroll
  for (int j = 0; j < K_; ++j) cnt[j] = 0.f;
  const bool do_cnt = (c == 0);

  for (int i = lo + tid; i < hi; i += 256) {
    float4 v = xp[i];
    int4 k4 = cp[i];
#pragma unroll
    for (int j = 0; j < K_; ++j) {
      acc[j] += (k4.x == j ? v.x : 0.f);
      acc[j] += (k4.y == j ? v.y : 0.f);
      acc[j] += (k4.z == j ? v.z : 0.f);
      acc[j] += (k4.w == j ? v.w : 0.f);
    }
    if (do_cnt) {
#pragma unroll
      for (int j = 0; j < K_; ++j) {
        cnt[j] += (float)((k4.x == j) + (k4.y == j) + (k4.z == j) + (k4.w == j));
      }
    }
  }

  // wave-level reduce (wave = 64 lanes), then one atomic per wave per bin
#pragma unroll
  for (int j = 0; j < K_; ++j) {
    float v = acc[j];
#pragma unroll
    for (int off = 32; off > 0; off >>= 1) v += __shfl_down(v, off, 64);
    if ((tid & 63) == 0) atomicAdd(&sums[(b * C_ + c) * K_ + j], v);
  }
  if (do_cnt) {
#pragma unroll
    for (int j = 0; j < K_; ++j) {
      float v = cnt[j];
#pragma unroll
      for (int off = 32; off > 0; off >>= 1) v += __shfl_down(v, off, 64);
      if ((tid & 63) == 0) atomicAdd(&counts[b * K_ + j], v);
    }
  }
}

// ---------------------------------------------------------------------------
// Kernel 3: per-block means normalization (redundant, from sums/counts — no
// separate k2 bubble) + per-pixel intra distance -> S2/Nk per cluster.
// grid (300, 8), block 256 = 64 pixel-lanes x 4 channel-groups.
// chunk-0 blocks additionally publish normalized means for k4.
// ---------------------------------------------------------------------------
__global__ __launch_bounds__(256) void k3_intra(
    const float* __restrict__ x, const int* __restrict__ cm,
    const float* __restrict__ sums, const float* __restrict__ counts,
    float* __restrict__ means, float* __restrict__ S2,
    float* __restrict__ Nk, float* __restrict__ indtot) {
  const int b = blockIdx.y;
  const int chunk = blockIdx.x;
  const int tid = threadIdx.x;
  const int lane_p = tid & 63;   // pixel-unit lane (one float4 = 4 pixels)
  const int grp = tid >> 6;      // channel group 0..3

  __shared__ float mlds[C_ * K_];   // 640 floats, layout [c*10+k]
  __shared__ float nrm[K_];
  __shared__ float4 pd[256];        // partial dots per thread
  __shared__ float s2b[K_];
  __shared__ float nkb[K_];

  // ---- local means normalization (replaces k2) ----
  for (int i = tid; i < C_ * K_; i += 256) {
    const int k = i % K_;
    mlds[i] = sums[b * C_ * K_ + i] / (counts[b * K_ + k] + 1e-10f);
  }
  if (tid < K_) { s2b[tid] = 0.f; nkb[tid] = 0.f; }
  __syncthreads();
  if (tid < K_) {
    float n2 = 0.f;
#pragma unroll
    for (int c = 0; c < C_; ++c) {
      const float mm = mlds[c * K_ + tid];
      n2 += mm * mm;
    }
    nrm[tid] = 1.f / fmaxf(sqrtf(n2), 1e-12f);
  }
  __syncthreads();
  for (int i = tid; i < C_ * K_; i += 256) mlds[i] *= nrm[i % K_];
  __syncthreads();
  if (chunk == 0) {
    for (int i = tid; i < C_ * K_; i += 256) means[b * C_ * K_ + i] = mlds[i];
  }

  // ---- intra distances ----
  const int p4 = chunk * 64 + lane_p;  // 0..19199
  const int4 k4 = ((const int4*)(cm + (size_t)b * HW_))[p4];
  const float4* __restrict__ xb = (const float4*)(x + (size_t)b * C_ * HW_);

  float d0 = 0.f, d1 = 0.f, d2 = 0.f, d3 = 0.f;
  const int c0 = grp * (C_ / 4);
#pragma unroll
  for (int cc = 0; cc < C_ / 4; ++cc) {
    const int c = c0 + cc;
    float4 v = xb[c * HW4_ + p4];
    const float* mr = &mlds[c * K_];
    d0 += v.x * mr[k4.x];
    d1 += v.y * mr[k4.y];
    d2 += v.z * mr[k4.z];
    d3 += v.w * mr[k4.w];
  }
  pd[tid] = make_float4(d0, d1, d2, d3);
  __syncthreads();

  if (grp == 0) {
    float4 a = pd[lane_p];
    float4 bb = pd[lane_p + 64];
    float4 cc = pd[lane_p + 128];
    float4 dd = pd[lane_p + 192];
    const float i0 = 0.5f * (1.f - (a.x + bb.x + cc.x + dd.x));
    const float i1 = 0.5f * (1.f - (a.y + bb.y + cc.y + dd.y));
    const float i2 = 0.5f * (1.f - (a.z + bb.z + cc.z + dd.z));
    const float i3 = 0.5f * (1.f - (a.w + bb.w + cc.w + dd.w));

    atomicAdd(&s2b[k4.x], i0 * i0);
    atomicAdd(&s2b[k4.y], i1 * i1);
    atomicAdd(&s2b[k4.z], i2 * i2);
    atomicAdd(&s2b[k4.w], i3 * i3);
    atomicAdd(&nkb[k4.x], i0 > ALPHA_ ? 1.f : 0.f);
    atomicAdd(&nkb[k4.y], i1 > ALPHA_ ? 1.f : 0.f);
    atomicAdd(&nkb[k4.z], i2 > ALPHA_ ? 1.f : 0.f);
    atomicAdd(&nkb[k4.w], i3 > ALPHA_ ? 1.f : 0.f);
  }
  __syncthreads();

  if (tid < K_) {
    atomicAdd(&S2[b * K_ + tid], s2b[tid]);
    atomicAdd(&Nk[b * K_ + tid], nkb[tid]);
    atomicAdd(indtot, nkb[tid]);
  }
}

// ---------------------------------------------------------------------------
// Kernel 4: inter hinge loss + finalize. One block.
// ---------------------------------------------------------------------------
__global__ __launch_bounds__(256) void k4_final(
    const float* __restrict__ means, const float* __restrict__ S2,
    const float* __restrict__ Nk, const float* __restrict__ indtot,
    float* __restrict__ out) {
  const int tid = threadIdx.x;

  float h2 = 0.f;
  for (int t = tid; t < B_ * 45; t += 256) {
    const int b = t / 45;
    int idx = t % 45;
    int k = 0, l = 0;
    for (k = 0; k < K_; ++k) {
      const int row = K_ - 1 - k;
      if (idx < row) { l = k + 1 + idx; break; }
      idx -= row;
    }
    float g = 0.f;
    for (int c = 0; c < C_; ++c)
      g += means[(b * C_ + c) * K_ + k] * means[(b * C_ + c) * K_ + l];
    const float inter_d = 0.5f * (1.f - g);
    const float h = fmaxf(DELTA_ - inter_d, 0.f);
    h2 += 2.f * h * h;  // (k,l) and (l,k)
  }

  __shared__ float red[256];
  red[tid] = h2;
  __syncthreads();
  for (int s = 128; s > 0; s >>= 1) {
    if (tid < s) red[tid] += red[tid + s];
    __syncthreads();
  }
  if (tid == 0) {
    const float inter = red[0] / (float)((K_ * (K_ - 1) / 2) * B_);
    float intra = 0.f;
    for (int i = 0; i < B_ * K_; ++i) {
      const float w = fmaxf(Nk[i], MIN_WEIGHT_) * (float)K_;
      intra += S2[i] / w;
    }
    intra /= (float)B_;
    if (!(indtot[0] > 0.f)) intra = 0.f;
    out[0] = intra + inter;
    out[1] = intra;
    out[2] = inter;
  }
}

extern "C" void kernel_launch(void* const* d_in, const int* in_sizes, int n_in,
                              void* d_out, int out_size, void* d_ws, size_t ws_size,
                              hipStream_t stream) {
  const float* x = (const float*)d_in[0];
  const int* cm = (const int*)d_in[1];

  float* ws = (float*)d_ws;
  float* sums = ws;             // 5120
  float* counts = ws + 5120;    // 80
  float* means = ws + 5200;     // 5120
  float* S2 = ws + 10320;       // 80
  float* Nk = ws + 10400;       // 80
  float* indtot = ws + 10480;   // 1

  // ws is re-poisoned to 0xAA before every call — zero the accumulators.
  hipMemsetAsync(d_ws, 0, 10481 * sizeof(float), stream);

  k1_sums<<<dim3(C_, B_, K1_SPLIT), 256, 0, stream>>>(x, cm, sums, counts);
  k3_intra<<<dim3(HW4_ / 64, B_), 256, 0, stream>>>(x, cm, sums, counts, means,
                                                    S2, Nk, indtot);
  k4_final<<<1, 256, 0, stream>>>(means, S2, Nk, indtot, (float*)d_out);
}